// Round 3
// baseline (1075.357 us; speedup 1.0000x reference)
//
#include <hip/hip_runtime.h>
#include <math.h>

// Problem constants (fixed-shape problem)
constexpr int BB = 8;      // batch
constexpr int CL = 2048;   // c_len
constexpr int QL = 512;    // q_len
constexpr int DM = 512;    // dim

constexpr int BM = 128, BN = 128, BK = 16;

enum { M_QP = 0, M_S = 1, M_ROW = 2, M_COL = 3 };

// ---------------------------------------------------------------------------
// Generic 128x128 fp32 tile GEMM, 256 threads, 8x8 per thread, K-step 16.
// Modes:
//  M_QP : Qp[b,j,n] = sum_d Q[j,b,d]*Wq[d,n] + bq[n]
//  M_S  : S[b,i,j]  = sum_d (C[i,b,d]*w3[d])*Qp[b,j,d] + c1[b,i]+q2[b,j]+bscal
//  M_ROW: Out[b,i,n] = sum_j p_row(i,j)*Bop[b,j,n],
//         p_row = Qm[b,j] ? exp(S-rmax[b,i])*rinv[b,i] : 0   (A & Bm GEMMs)
//  M_COL: T[b,j,n] += sum_i p_col(i,j)*C[i,b,n]  (split-K=4, atomicAdd)
//         p_col = Cm[b,i] ? exp(S-cmax[b,j])*cinv[b,j] : 0
// ---------------------------------------------------------------------------
template <int MODE>
__global__ __launch_bounds__(256) void gemm128(
    const float* __restrict__ Abase, const float* __restrict__ Bbase,
    float* __restrict__ Cbase,
    const float* __restrict__ w3,
    const float* __restrict__ c1v, const float* __restrict__ q2v,
    const float* __restrict__ bscal, const float* __restrict__ bq,
    const float* __restrict__ smax, const float* __restrict__ sinv,
    const int* __restrict__ msk)
{
  __shared__ float As[BK][BM];
  __shared__ float Bs[BK][BN];
  const int tid = threadIdx.x;
  int b, ks0 = 0, Ksz;
  if constexpr (MODE == M_COL) {
    b = blockIdx.z >> 2; ks0 = (blockIdx.z & 3) * (CL / 4); Ksz = CL / 4;
  } else {
    b = blockIdx.z; Ksz = (MODE == M_ROW) ? QL : DM;
  }
  const int m0 = blockIdx.x * BM, n0 = blockIdx.y * BN;

  // ---- A staging setup
  const int ar = tid >> 1, akc = (tid & 1) * 8;    // transposed-load path
  const int ck = tid >> 5, cm4 = (tid & 31) * 4;   // direct-load path (COL)
  const float* Aptr = nullptr;
  float rmx = 0.f, rin = 0.f;
  float4 cmx4 = {0, 0, 0, 0}, cin4 = {0, 0, 0, 0};
  if constexpr (MODE == M_QP || MODE == M_S) {
    Aptr = Abase + (size_t)(m0 + ar) * (BB * DM) + (size_t)b * DM + akc;
  } else if constexpr (MODE == M_ROW) {
    Aptr = Abase + (size_t)b * CL * QL + (size_t)(m0 + ar) * QL + akc;
    rmx = smax[b * CL + m0 + ar];
    rin = sinv[b * CL + m0 + ar];
  } else {  // M_COL
    Aptr = Abase + (size_t)b * CL * QL + (size_t)ks0 * QL + m0 + cm4;
    cmx4 = *(const float4*)(smax + b * QL + m0 + cm4);
    cin4 = *(const float4*)(sinv + b * QL + m0 + cm4);
  }

  // ---- B staging setup (NOTE: bk NOT folded into Bptr; the stage loop
  // adds (k0+kk)*ldb with kk = bk + h*8 — folding it in double-counted bk)
  const int bk = tid >> 5, bn4 = (tid & 31) * 4;   // direct path
  const int brn = tid >> 1, bkc = (tid & 1) * 8;   // BT path (M_S)
  const float* Bptr = nullptr;
  int ldb = 0;
  if constexpr (MODE == M_QP) {
    Bptr = Bbase + n0 + bn4; ldb = DM;
  } else if constexpr (MODE == M_S) {
    Bptr = Bbase + (size_t)b * QL * DM + (size_t)(n0 + brn) * DM + bkc;
  } else if constexpr (MODE == M_ROW) {
    Bptr = Bbase + (size_t)b * QL * DM + n0 + bn4; ldb = DM;
  } else {  // M_COL : B = C rows (i = k index)
    Bptr = Bbase + (size_t)ks0 * (BB * DM) + (size_t)b * DM + n0 + bn4;
    ldb = BB * DM;
  }

  float acc[8][8] = {};

  for (int k0 = 0; k0 < Ksz; k0 += BK) {
    // ---- stage A into As[k][m] (transposed for row-major A)
    if constexpr (MODE != M_COL) {
      float4 v0 = *(const float4*)(Aptr + k0);
      float4 v1 = *(const float4*)(Aptr + k0 + 4);
      float va[8] = {v0.x, v0.y, v0.z, v0.w, v1.x, v1.y, v1.z, v1.w};
      if constexpr (MODE == M_S) {
        float4 w0 = *(const float4*)(w3 + k0 + akc);
        float4 w1 = *(const float4*)(w3 + k0 + akc + 4);
        float ww[8] = {w0.x, w0.y, w0.z, w0.w, w1.x, w1.y, w1.z, w1.w};
        #pragma unroll
        for (int e = 0; e < 8; e++) va[e] *= ww[e];
      }
      if constexpr (MODE == M_ROW) {
        #pragma unroll
        for (int e = 0; e < 8; e++) {
          const int j = k0 + akc + e;
          va[e] = msk[j * BB + b] ? expf(va[e] - rmx) * rin : 0.f;
        }
      }
      #pragma unroll
      for (int e = 0; e < 8; e++) As[akc + e][ar] = va[e];
    } else {
      #pragma unroll
      for (int h = 0; h < 2; h++) {
        const int kk = ck + h * 8;
        float4 v = *(const float4*)(Aptr + (size_t)(k0 + kk) * QL);
        const int mk = msk[(ks0 + k0 + kk) * BB + b];
        float4 r;
        r.x = mk ? expf(v.x - cmx4.x) * cin4.x : 0.f;
        r.y = mk ? expf(v.y - cmx4.y) * cin4.y : 0.f;
        r.z = mk ? expf(v.z - cmx4.z) * cin4.z : 0.f;
        r.w = mk ? expf(v.w - cmx4.w) * cin4.w : 0.f;
        *(float4*)&As[kk][cm4] = r;
      }
    }
    // ---- stage B into Bs[k][n]
    if constexpr (MODE == M_S) {
      float4 v0 = *(const float4*)(Bptr + k0);
      float4 v1 = *(const float4*)(Bptr + k0 + 4);
      float vb[8] = {v0.x, v0.y, v0.z, v0.w, v1.x, v1.y, v1.z, v1.w};
      #pragma unroll
      for (int e = 0; e < 8; e++) Bs[bkc + e][brn] = vb[e];
    } else {
      #pragma unroll
      for (int h = 0; h < 2; h++) {
        const int kk = bk + h * 8;
        float4 v = *(const float4*)(Bptr + (size_t)(k0 + kk) * ldb);
        *(float4*)&Bs[kk][bn4] = v;
      }
    }
    __syncthreads();
    // ---- compute
    #pragma unroll
    for (int kk = 0; kk < BK; kk++) {
      float a[8], bv[8];
      *(float4*)(a)      = *(const float4*)&As[kk][(tid >> 4) * 8];
      *(float4*)(a + 4)  = *(const float4*)&As[kk][(tid >> 4) * 8 + 4];
      *(float4*)(bv)     = *(const float4*)&Bs[kk][(tid & 15) * 8];
      *(float4*)(bv + 4) = *(const float4*)&Bs[kk][(tid & 15) * 8 + 4];
      #pragma unroll
      for (int r = 0; r < 8; r++)
        #pragma unroll
        for (int c = 0; c < 8; c++)
          acc[r][c] = fmaf(a[r], bv[c], acc[r][c]);
    }
    __syncthreads();
  }

  // ---- epilogue
  const int mo = m0 + (tid >> 4) * 8;
  const int no = n0 + (tid & 15) * 8;
  if constexpr (MODE == M_QP) {
    float bqv[8];
    *(float4*)(bqv)     = *(const float4*)(bq + no);
    *(float4*)(bqv + 4) = *(const float4*)(bq + no + 4);
    float* Cp = Cbase + (size_t)b * QL * DM;
    #pragma unroll
    for (int r = 0; r < 8; r++) {
      float4 o0 = {acc[r][0] + bqv[0], acc[r][1] + bqv[1],
                   acc[r][2] + bqv[2], acc[r][3] + bqv[3]};
      float4 o1 = {acc[r][4] + bqv[4], acc[r][5] + bqv[5],
                   acc[r][6] + bqv[6], acc[r][7] + bqv[7]};
      *(float4*)(Cp + (size_t)(mo + r) * DM + no) = o0;
      *(float4*)(Cp + (size_t)(mo + r) * DM + no + 4) = o1;
    }
  } else if constexpr (MODE == M_S) {
    float an[8];
    *(float4*)(an)     = *(const float4*)(q2v + b * QL + no);
    *(float4*)(an + 4) = *(const float4*)(q2v + b * QL + no + 4);
    const float sb = bscal[0];
    float* Cp = Cbase + (size_t)b * CL * QL;
    #pragma unroll
    for (int r = 0; r < 8; r++) {
      const float am = c1v[b * CL + mo + r] + sb;
      float4 o0 = {acc[r][0] + am + an[0], acc[r][1] + am + an[1],
                   acc[r][2] + am + an[2], acc[r][3] + am + an[3]};
      float4 o1 = {acc[r][4] + am + an[4], acc[r][5] + am + an[5],
                   acc[r][6] + am + an[6], acc[r][7] + am + an[7]};
      *(float4*)(Cp + (size_t)(mo + r) * QL + no) = o0;
      *(float4*)(Cp + (size_t)(mo + r) * QL + no + 4) = o1;
    }
  } else if constexpr (MODE == M_ROW) {
    // Cbase = d_out + slot; out row (i) stride = BB*4*DM, batch stride 4*DM
    float* Cp = Cbase + (size_t)b * 4 * DM;
    #pragma unroll
    for (int r = 0; r < 8; r++) {
      float4 o0 = {acc[r][0], acc[r][1], acc[r][2], acc[r][3]};
      float4 o1 = {acc[r][4], acc[r][5], acc[r][6], acc[r][7]};
      *(float4*)(Cp + (size_t)(mo + r) * (BB * 4 * DM) + no) = o0;
      *(float4*)(Cp + (size_t)(mo + r) * (BB * 4 * DM) + no + 4) = o1;
    }
  } else {  // M_COL
    float* Cp = Cbase + (size_t)b * QL * DM;
    #pragma unroll
    for (int r = 0; r < 8; r++)
      #pragma unroll
      for (int c = 0; c < 8; c++)
        atomicAdd(Cp + (size_t)(mo + r) * DM + no + c, acc[r][c]);
  }
}

// ---------------------------------------------------------------------------
// out[row] = dot(mat_row, w), rows of length 512. One wave per row.
// MAP==0: row rid is contiguous (Qp layout).  MAP==1: rid=b*2048+i -> C row.
// ---------------------------------------------------------------------------
template <int MAP>
__global__ __launch_bounds__(256) void rowdot(const float* __restrict__ src,
                                              const float* __restrict__ w,
                                              float* __restrict__ out)
{
  const int rid = blockIdx.x * 4 + (threadIdx.x >> 6);
  const int lane = threadIdx.x & 63;
  const float* row;
  if constexpr (MAP == 1) {
    const int b = rid >> 11, i = rid & 2047;
    row = src + ((size_t)i * BB + b) * DM;
  } else {
    row = src + (size_t)rid * DM;
  }
  float4 v0 = *(const float4*)(row + lane * 8);
  float4 v1 = *(const float4*)(row + lane * 8 + 4);
  float4 w0 = *(const float4*)(w + lane * 8);
  float4 w1 = *(const float4*)(w + lane * 8 + 4);
  float s = v0.x * w0.x + v0.y * w0.y + v0.z * w0.z + v0.w * w0.w +
            v1.x * w1.x + v1.y * w1.y + v1.z * w1.z + v1.w * w1.w;
  #pragma unroll
  for (int off = 32; off; off >>= 1) s += __shfl_xor(s, off);
  if (lane == 0) out[rid] = s;
}

// ---------------------------------------------------------------------------
// Row softmax stats: per (b,i) over j in [0,512), masked by Q_mask[j,b].
// ---------------------------------------------------------------------------
__global__ __launch_bounds__(256) void row_stats(const float* __restrict__ S,
    const int* __restrict__ qm, float* __restrict__ rmax, float* __restrict__ rinv)
{
  const int rid = blockIdx.x * 4 + (threadIdx.x >> 6);  // b*2048 + i
  const int lane = threadIdx.x & 63;
  const int b = rid >> 11;
  const float* row = S + (size_t)rid * QL;
  float4 v0 = *(const float4*)(row + lane * 8);
  float4 v1 = *(const float4*)(row + lane * 8 + 4);
  float va[8] = {v0.x, v0.y, v0.z, v0.w, v1.x, v1.y, v1.z, v1.w};
  int mk[8];
  float m = -INFINITY;
  #pragma unroll
  for (int e = 0; e < 8; e++) {
    mk[e] = qm[(lane * 8 + e) * BB + b];
    if (mk[e]) m = fmaxf(m, va[e]);
  }
  #pragma unroll
  for (int off = 32; off; off >>= 1) m = fmaxf(m, __shfl_xor(m, off));
  float s = 0.f;
  #pragma unroll
  for (int e = 0; e < 8; e++) if (mk[e]) s += expf(va[e] - m);
  #pragma unroll
  for (int off = 32; off; off >>= 1) s += __shfl_xor(s, off);
  if (lane == 0) { rmax[rid] = m; rinv[rid] = 1.f / s; }
}

// ---------------------------------------------------------------------------
// Col softmax stats, chunked over i. Thread t = b*512+j, chunk = blockIdx.y.
// ---------------------------------------------------------------------------
constexpr int CH = 16;  // i-chunks of 128

__global__ __launch_bounds__(256) void col_part(const float* __restrict__ S,
    const int* __restrict__ cm, float* __restrict__ pmax, float* __restrict__ psum)
{
  const int t = blockIdx.x * 256 + threadIdx.x;  // 0..4095 = b*512+j
  const int ch = blockIdx.y;
  const int b = t >> 9, j = t & 511;
  const float* col = S + (size_t)b * CL * QL + j;
  float m = -INFINITY, s = 0.f;
  const int i0 = ch * (CL / CH);
  for (int i = 0; i < CL / CH; i++) {
    const int ig = i0 + i;
    const float v = col[(size_t)ig * QL];
    if (cm[ig * BB + b]) {
      const float nm = fmaxf(m, v);
      s = s * expf(m - nm) + expf(v - nm);
      m = nm;
    }
  }
  pmax[ch * 4096 + t] = m;
  psum[ch * 4096 + t] = s;
}

__global__ __launch_bounds__(256) void col_comb(const float* __restrict__ pmax,
    const float* __restrict__ psum, float* __restrict__ cmax, float* __restrict__ cinv)
{
  const int t = blockIdx.x * 256 + threadIdx.x;  // 0..4095
  float m = -INFINITY;
  #pragma unroll
  for (int ch = 0; ch < CH; ch++) m = fmaxf(m, pmax[ch * 4096 + t]);
  float s = 0.f;
  #pragma unroll
  for (int ch = 0; ch < CH; ch++) {
    const float pm = pmax[ch * 4096 + t];
    if (pm > -INFINITY) s += psum[ch * 4096 + t] * expf(pm - m);
  }
  cmax[t] = m;
  cinv[t] = 1.f / s;
}

// ---------------------------------------------------------------------------
// Final assembly: out rows (i*B+b), 2048 floats. Slot1 (A) already final;
// writes slot0 = C, slot2 = C*A, slot3 = C*Bm (Bm was staged in slot3).
// ---------------------------------------------------------------------------
__global__ __launch_bounds__(256) void assemble(const float* __restrict__ Cin,
                                                float* __restrict__ out)
{
  const size_t f = (size_t)blockIdx.x * 256 + threadIdx.x;  // 16384*128 float4s
  const size_t row = f >> 7, d4 = f & 127;
  const float4 c = ((const float4*)Cin)[row * 128 + d4];
  float4* orow = (float4*)out + row * 512;
  const float4 a = orow[128 + d4];
  const float4 bm = orow[384 + d4];
  orow[d4] = c;
  float4 ca = {c.x * a.x, c.y * a.y, c.z * a.z, c.w * a.w};
  float4 cb = {c.x * bm.x, c.y * bm.y, c.z * bm.z, c.w * bm.w};
  orow[256 + d4] = ca;
  orow[384 + d4] = cb;
}

// ---------------------------------------------------------------------------
extern "C" void kernel_launch(void* const* d_in, const int* in_sizes, int n_in,
                              void* d_out, int out_size, void* d_ws, size_t ws_size,
                              hipStream_t stream)
{
  const float* C  = (const float*)d_in[0];
  const float* Q  = (const float*)d_in[1];
  const int*   Cm = (const int*)d_in[2];
  const int*   Qm = (const int*)d_in[3];
  const float* Wq = (const float*)d_in[4];
  const float* bq = (const float*)d_in[5];
  const float* w1 = (const float*)d_in[6];
  const float* w2 = (const float*)d_in[7];
  const float* w3 = (const float*)d_in[8];
  const float* bs = (const float*)d_in[9];
  float* out = (float*)d_out;
  float* ws  = (float*)d_ws;

  float* Qp   = ws;                       // 2,097,152
  float* S    = ws + 2097152;             // 8,388,608
  float* T    = ws + 10485760;            // 2,097,152
  float* c1   = ws + 12582912;            // 16,384
  float* q2   = ws + 12599296;            // 4,096
  float* rmax = ws + 12603392;            // 16,384
  float* rinv = ws + 12619776;            // 16,384
  float* cmax = ws + 12636160;            // 4,096
  float* cinv = ws + 12640256;            // 4,096
  float* pmax = ws + 12644352;            // 65,536
  float* psum = ws + 12709888;            // 65,536  (total ~48.7 MiB)

  hipMemsetAsync(T, 0, (size_t)2097152 * 4, stream);

  // Qp = Q @ Wq + bq
  gemm128<M_QP><<<dim3(4, 4, BB), 256, 0, stream>>>(
      Q, Wq, Qp, nullptr, nullptr, nullptr, nullptr, bq, nullptr, nullptr, nullptr);
  // c1[b,i] = w1 . C_i ;  q2[b,j] = w2 . Qp_j
  rowdot<1><<<4096, 256, 0, stream>>>(C, w1, c1);
  rowdot<0><<<1024, 256, 0, stream>>>(Qp, w2, q2);
  // S = (C*w3) @ Qp^T + c1 + q2 + b
  gemm128<M_S><<<dim3(16, 4, BB), 256, 0, stream>>>(
      C, Qp, S, w3, c1, q2, bs, nullptr, nullptr, nullptr, nullptr);
  // softmax stats
  row_stats<<<4096, 256, 0, stream>>>(S, Qm, rmax, rinv);
  col_part<<<dim3(16, CH), 256, 0, stream>>>(S, Cm, pmax, psum);
  col_comb<<<16, 256, 0, stream>>>(pmax, psum, cmax, cinv);
  // A = S_row @ Qp  -> out slot 1
  gemm128<M_ROW><<<dim3(16, 4, BB), 256, 0, stream>>>(
      S, Qp, out + 512, nullptr, nullptr, nullptr, nullptr, nullptr, rmax, rinv, Qm);
  // T = S_col^T @ C  (split-K=4, atomic)
  gemm128<M_COL><<<dim3(4, 4, BB * 4), 256, 0, stream>>>(
      S, C, T, nullptr, nullptr, nullptr, nullptr, nullptr, cmax, cinv, Cm);
  // Bm = S_row @ T  -> out slot 3 (temporarily raw Bm)
  gemm128<M_ROW><<<dim3(16, 4, BB), 256, 0, stream>>>(
      S, T, out + 1536, nullptr, nullptr, nullptr, nullptr, nullptr, rmax, rinv, Qm);
  // slot0 = C, slot2 = C*A, slot3 = C*Bm
  assemble<<<8192, 256, 0, stream>>>(C, out);
}

// Round 5
// 504.003 us; speedup vs baseline: 2.1336x; 2.1336x over previous
//
#include <hip/hip_runtime.h>
#include <math.h>

// Problem constants (fixed-shape)
constexpr int BB = 8;      // batch
constexpr int CL = 2048;   // c_len
constexpr int QL = 512;    // q_len
constexpr int DM = 512;    // dim

typedef short          bf16x8 __attribute__((ext_vector_type(8)));
typedef unsigned short us8    __attribute__((ext_vector_type(8)));
typedef float          f32x4  __attribute__((ext_vector_type(4)));

__device__ __forceinline__ unsigned short f2b(float f) {
  union { float f; unsigned u; } v; v.f = f;
  return (unsigned short)((v.u + 0x7FFFu + ((v.u >> 16) & 1u)) >> 16);
}

// ---------------------------------------------------------------------------
// MFMA bf16 GEMM template. Both operands stored row-major over K:
//   A[b][row][k] (stride sA, batch batA), B[b][col][k] (stride sB, batch batB)
// Wave = 64x64 tile (4x4 frags of 16x16x32), block = WR x WC waves.
// Frag conventions (gfx950 mfma_f32_16x16x32_bf16):
//   A/B: lane l holds 8 bf16 at [row/col = l&15][k = (l>>4)*8 .. +8)
//        (identical lane->k map for A and B => result invariant to the
//         intra-fragment k permutation; only C/D layout must be exact)
//   D:   col = lane&15, row = (lane>>4)*4 + reg   (HW-verified, m89/m91)
// Modes: G_QP (+bq[col] -> f32), G_S (+c1[row]+q2[col]+b -> f32),
//        G_SLOT (f32 to out-slot layout), G_TT (bf16 out).
// ---------------------------------------------------------------------------
enum { G_QP = 0, G_S = 1, G_SLOT = 2, G_TT = 3 };

template <int MODE, int WR, int WC>
__global__ __launch_bounds__(WR * WC * 64) void mgemm(
    const unsigned short* __restrict__ A, int sA, size_t batA,
    const unsigned short* __restrict__ B, int sB, size_t batB,
    int K,
    float* __restrict__ Of, unsigned short* __restrict__ Ob,
    int sD, size_t batD,
    const float* __restrict__ e1, const float* __restrict__ e2,
    const float* __restrict__ e3)
{
  const int tid = threadIdx.x, b = blockIdx.z;
  const int wave = tid >> 6, lane = tid & 63;
  const int wr = wave / WC, wc = wave % WC;
  const int m0 = blockIdx.x * (WR * 64) + wr * 64;
  const int n0 = blockIdx.y * (WC * 64) + wc * 64;
  const int l15 = lane & 15, lk8 = (lane >> 4) * 8;

  const unsigned short* ap = A + batA * b + (size_t)(m0 + l15) * sA + lk8;
  const unsigned short* bp = B + batB * b + (size_t)(n0 + l15) * sB + lk8;

  f32x4 acc[4][4];
  #pragma unroll
  for (int mr = 0; mr < 4; mr++)
    #pragma unroll
    for (int nc = 0; nc < 4; nc++) acc[mr][nc] = (f32x4){0.f, 0.f, 0.f, 0.f};

  for (int k0 = 0; k0 < K; k0 += 32) {
    bf16x8 af[4], bf[4];
    #pragma unroll
    for (int mr = 0; mr < 4; mr++)
      af[mr] = *(const bf16x8*)(ap + (size_t)mr * 16 * sA + k0);
    #pragma unroll
    for (int nc = 0; nc < 4; nc++)
      bf[nc] = *(const bf16x8*)(bp + (size_t)nc * 16 * sB + k0);
    #pragma unroll
    for (int mr = 0; mr < 4; mr++)
      #pragma unroll
      for (int nc = 0; nc < 4; nc++)
        acc[mr][nc] = __builtin_amdgcn_mfma_f32_16x16x32_bf16(
            af[mr], bf[nc], acc[mr][nc], 0, 0, 0);
  }

  const int r0 = (lane >> 4) * 4;
  #pragma unroll
  for (int mr = 0; mr < 4; mr++) {
    #pragma unroll
    for (int nc = 0; nc < 4; nc++) {
      const int col = n0 + nc * 16 + l15;
      float addc = 0.f;
      if constexpr (MODE == G_QP) addc = e1[col];
      if constexpr (MODE == G_S)  addc = e2[b * QL + col] + e3[0];
      #pragma unroll
      for (int r = 0; r < 4; r++) {
        const int row = m0 + mr * 16 + r0 + r;
        float v = acc[mr][nc][r] + addc;
        if constexpr (MODE == G_S) v += e1[b * CL + row];
        if constexpr (MODE == G_TT)
          Ob[batD * b + (size_t)row * sD + col] = f2b(v);
        else
          Of[batD * b + (size_t)row * sD + col] = v;
      }
    }
  }
}

// ---------------------------------------------------------------------------
// Elementwise fp32 -> bf16 cast, 8 elems/thread (layout preserved).
// ---------------------------------------------------------------------------
__global__ __launch_bounds__(256) void cast8(const float* __restrict__ src,
                                             unsigned short* __restrict__ dst)
{
  const int g = blockIdx.x * 256 + threadIdx.x;
  const float4 v0 = *((const float4*)src + g * 2);
  const float4 v1 = *((const float4*)src + g * 2 + 1);
  us8 r = {f2b(v0.x), f2b(v0.y), f2b(v0.z), f2b(v0.w),
           f2b(v1.x), f2b(v1.y), f2b(v1.z), f2b(v1.w)};
  *((us8*)dst + g) = r;
}

// ---------------------------------------------------------------------------
// Cw3b[b][i][d] = bf16(C[i][b][d] * w3[d]); d stays innermost (no transpose).
// ---------------------------------------------------------------------------
__global__ __launch_bounds__(256) void build_cw3(const float* __restrict__ C,
                                                 const float* __restrict__ w3,
                                                 unsigned short* __restrict__ dst)
{
  const int g = blockIdx.x * 256 + threadIdx.x;   // 16384 rows * 64
  const int orow = g >> 6, d0 = (g & 63) * 8;     // orow = b*CL + i
  const int b = orow >> 11, i = orow & 2047;
  const float* s = C + ((size_t)i * BB + b) * DM + d0;
  const float4 v0 = *(const float4*)s, v1 = *(const float4*)(s + 4);
  const float4 w0 = *(const float4*)(w3 + d0), w1 = *(const float4*)(w3 + d0 + 4);
  us8 r = {f2b(v0.x * w0.x), f2b(v0.y * w0.y), f2b(v0.z * w0.z), f2b(v0.w * w0.w),
           f2b(v1.x * w1.x), f2b(v1.y * w1.y), f2b(v1.z * w1.z), f2b(v1.w * w1.w)};
  *(us8*)(dst + (size_t)orow * DM + d0) = r;
}

// ---------------------------------------------------------------------------
// Tiled 64x64 transpose, fp32 src -> bf16 dst: dst[b][c][r] = src[b][r][c].
// ---------------------------------------------------------------------------
__global__ __launch_bounds__(256) void transbf(const float* __restrict__ src,
                                               unsigned short* __restrict__ dst,
                                               int sSrc, int sDst,
                                               size_t batSrc, size_t batDst)
{
  __shared__ float t[64][65];
  const int b = blockIdx.z;
  const int r0 = blockIdx.x * 64, c0 = blockIdx.y * 64;
  const int tx = threadIdx.x & 63, ty = threadIdx.x >> 6;  // ty 0..3
  const float* S = src + batSrc * b;
  unsigned short* D = dst + batDst * b;
  #pragma unroll
  for (int rr = 0; rr < 16; rr++) {
    const int r = ty * 16 + rr;
    t[r][tx] = S[(size_t)(r0 + r) * sSrc + c0 + tx];
  }
  __syncthreads();
  #pragma unroll
  for (int rr = 0; rr < 16; rr++) {
    const int c = ty * 16 + rr;
    D[(size_t)(c0 + c) * sDst + r0 + tx] = f2b(t[tx][c]);
  }
}

// ---------------------------------------------------------------------------
// P_rowb[b][i][j] = Qm[j,b] ? bf16(exp(S-rmax[b,i])*rinv[b,i]) : 0
// ---------------------------------------------------------------------------
__global__ __launch_bounds__(256) void build_prow(
    const float* __restrict__ S, const int* __restrict__ qm,
    const float* __restrict__ rmax, const float* __restrict__ rinv,
    unsigned short* __restrict__ dst)
{
  const int g = blockIdx.x * 256 + threadIdx.x;
  const int row = g >> 6, j0 = (g & 63) * 8;      // row = b*CL + i
  const int b = row >> 11;
  const float* s = S + (size_t)row * QL + j0;
  const float4 v0 = *(const float4*)s, v1 = *(const float4*)(s + 4);
  const float m = rmax[row], iv = rinv[row];
  const float va[8] = {v0.x, v0.y, v0.z, v0.w, v1.x, v1.y, v1.z, v1.w};
  us8 r;
  #pragma unroll
  for (int e = 0; e < 8; e++) {
    const int mk = qm[(j0 + e) * BB + b];
    r[e] = mk ? f2b(expf(va[e] - m) * iv) : (unsigned short)0;
  }
  *(us8*)(dst + (size_t)row * QL + j0) = r;
}

// ---------------------------------------------------------------------------
// P_colTb[b][j][i] = Cm[i,b] ? bf16(exp(S[b][i][j]-cmax[b,j])*cinv[b,j]) : 0
// (tiled transpose of S with the col-softmax transform applied on write)
// ---------------------------------------------------------------------------
__global__ __launch_bounds__(256) void build_pcolt(
    const float* __restrict__ Sm, const int* __restrict__ cm,
    const float* __restrict__ cmax, const float* __restrict__ cinv,
    unsigned short* __restrict__ dst)
{
  __shared__ float t[64][65];
  const int b = blockIdx.z;
  const int i0 = blockIdx.x * 64, j0 = blockIdx.y * 64;
  const int tx = threadIdx.x & 63, ty = threadIdx.x >> 6;
  const float* S = Sm + (size_t)b * CL * QL;
  #pragma unroll
  for (int rr = 0; rr < 16; rr++) {
    const int i = ty * 16 + rr;
    t[i][tx] = S[(size_t)(i0 + i) * QL + j0 + tx];
  }
  __syncthreads();
  const int cmv = cm[(i0 + tx) * BB + b];
  #pragma unroll
  for (int rr = 0; rr < 16; rr++) {
    const int j = j0 + ty * 16 + rr;
    const float mj = cmax[b * QL + j], ivj = cinv[b * QL + j];
    const float v = t[tx][ty * 16 + rr];
    dst[(size_t)b * QL * CL + (size_t)j * CL + i0 + tx] =
        cmv ? f2b(expf(v - mj) * ivj) : (unsigned short)0;
  }
}

// ---------------------------------------------------------------------------
// out[row] = dot(mat_row, w), rows of length 512. One wave per row.
// ---------------------------------------------------------------------------
template <int MAP>
__global__ __launch_bounds__(256) void rowdot(const float* __restrict__ src,
                                              const float* __restrict__ w,
                                              float* __restrict__ out)
{
  const int rid = blockIdx.x * 4 + (threadIdx.x >> 6);
  const int lane = threadIdx.x & 63;
  const float* row;
  if constexpr (MAP == 1) {
    const int b = rid >> 11, i = rid & 2047;
    row = src + ((size_t)i * BB + b) * DM;
  } else {
    row = src + (size_t)rid * DM;
  }
  float4 v0 = *(const float4*)(row + lane * 8);
  float4 v1 = *(const float4*)(row + lane * 8 + 4);
  float4 w0 = *(const float4*)(w + lane * 8);
  float4 w1 = *(const float4*)(w + lane * 8 + 4);
  float s = v0.x * w0.x + v0.y * w0.y + v0.z * w0.z + v0.w * w0.w +
            v1.x * w1.x + v1.y * w1.y + v1.z * w1.z + v1.w * w1.w;
  #pragma unroll
  for (int off = 32; off; off >>= 1) s += __shfl_xor(s, off);
  if (lane == 0) out[rid] = s;
}

// ---------------------------------------------------------------------------
// Row softmax stats over j (masked by Q_mask[j,b]).
// ---------------------------------------------------------------------------
__global__ __launch_bounds__(256) void row_stats(const float* __restrict__ S,
    const int* __restrict__ qm, float* __restrict__ rmax, float* __restrict__ rinv)
{
  const int rid = blockIdx.x * 4 + (threadIdx.x >> 6);  // b*CL + i
  const int lane = threadIdx.x & 63;
  const int b = rid >> 11;
  const float* row = S + (size_t)rid * QL;
  float4 v0 = *(const float4*)(row + lane * 8);
  float4 v1 = *(const float4*)(row + lane * 8 + 4);
  float va[8] = {v0.x, v0.y, v0.z, v0.w, v1.x, v1.y, v1.z, v1.w};
  int mk[8];
  float m = -INFINITY;
  #pragma unroll
  for (int e = 0; e < 8; e++) {
    mk[e] = qm[(lane * 8 + e) * BB + b];
    if (mk[e]) m = fmaxf(m, va[e]);
  }
  #pragma unroll
  for (int off = 32; off; off >>= 1) m = fmaxf(m, __shfl_xor(m, off));
  float s = 0.f;
  #pragma unroll
  for (int e = 0; e < 8; e++) if (mk[e]) s += expf(va[e] - m);
  #pragma unroll
  for (int off = 32; off; off >>= 1) s += __shfl_xor(s, off);
  if (lane == 0) { rmax[rid] = m; rinv[rid] = 1.f / s; }
}

// ---------------------------------------------------------------------------
// Col softmax stats, chunked over i.
// ---------------------------------------------------------------------------
constexpr int CH = 16;

__global__ __launch_bounds__(256) void col_part(const float* __restrict__ S,
    const int* __restrict__ cm, float* __restrict__ pmax, float* __restrict__ psum)
{
  const int t = blockIdx.x * 256 + threadIdx.x;  // b*QL + j
  const int ch = blockIdx.y;
  const int b = t >> 9, j = t & 511;
  const float* col = S + (size_t)b * CL * QL + j;
  float m = -INFINITY, s = 0.f;
  const int i0 = ch * (CL / CH);
  for (int i = 0; i < CL / CH; i++) {
    const int ig = i0 + i;
    const float v = col[(size_t)ig * QL];
    if (cm[ig * BB + b]) {
      const float nm = fmaxf(m, v);
      s = s * expf(m - nm) + expf(v - nm);
      m = nm;
    }
  }
  pmax[ch * 4096 + t] = m;
  psum[ch * 4096 + t] = s;
}

__global__ __launch_bounds__(256) void col_comb(const float* __restrict__ pmax,
    const float* __restrict__ psum, float* __restrict__ cmax, float* __restrict__ cinv)
{
  const int t = blockIdx.x * 256 + threadIdx.x;
  float m = -INFINITY;
  #pragma unroll
  for (int ch = 0; ch < CH; ch++) m = fmaxf(m, pmax[ch * 4096 + t]);
  float s = 0.f;
  #pragma unroll
  for (int ch = 0; ch < CH; ch++) {
    const float pm = pmax[ch * 4096 + t];
    if (pm > -INFINITY) s += psum[ch * 4096 + t] * expf(pm - m);
  }
  cmax[t] = m;
  cinv[t] = 1.f / s;
}

// ---------------------------------------------------------------------------
// Final assembly: slot0 = C, slot2 = C*A, slot3 = C*Bm (Bm staged in slot3).
// ---------------------------------------------------------------------------
__global__ __launch_bounds__(256) void assemble(const float* __restrict__ Cin,
                                                float* __restrict__ out)
{
  const size_t f = (size_t)blockIdx.x * 256 + threadIdx.x;
  const size_t row = f >> 7, d4 = f & 127;
  const float4 c = ((const float4*)Cin)[row * 128 + d4];
  float4* orow = (float4*)out + row * 512;
  const float4 a = orow[128 + d4];
  const float4 bm = orow[384 + d4];
  orow[d4] = c;
  float4 ca = {c.x * a.x, c.y * a.y, c.z * a.z, c.w * a.w};
  float4 cb = {c.x * bm.x, c.y * bm.y, c.z * bm.z, c.w * bm.w};
  orow[256 + d4] = ca;
  orow[384 + d4] = cb;
}

// ---------------------------------------------------------------------------
extern "C" void kernel_launch(void* const* d_in, const int* in_sizes, int n_in,
                              void* d_out, int out_size, void* d_ws, size_t ws_size,
                              hipStream_t stream)
{
  const float* C  = (const float*)d_in[0];
  const float* Q  = (const float*)d_in[1];
  const int*   Cm = (const int*)d_in[2];
  const int*   Qm = (const int*)d_in[3];
  const float* Wq = (const float*)d_in[4];
  const float* bq = (const float*)d_in[5];
  const float* w1 = (const float*)d_in[6];
  const float* w2 = (const float*)d_in[7];
  const float* w3 = (const float*)d_in[8];
  const float* bs = (const float*)d_in[9];
  float* out = (float*)d_out;
  float* ws  = (float*)d_ws;

  // fp32 region (float offsets)
  float* S    = ws;                 //  8,388,608 (dead after P-builds)
  float* Qp   = ws + 8388608;       //  2,097,152
  float* c1   = ws + 10485760;      //  16,384
  float* q2   = ws + 10502144;      //  4,096
  float* rmax = ws + 10506240;      //  16,384
  float* rinv = ws + 10522624;      //  16,384
  float* cmax = ws + 10539008;      //  4,096
  float* cinv = ws + 10543104;      //  4,096
  float* pmax = ws + 10547200;      //  65,536
  float* psum = ws + 10612736;      //  65,536
  // bf16 region (ushort offsets from bfp); peak d_ws use ~85 MB
  unsigned short* bfp   = (unsigned short*)(ws + 10678272);
  unsigned short* Qb    = bfp;             //  2,097,152 (dead after QP-GEMM)
  unsigned short* Qpb   = bfp;             //  ALIAS Qb (dead after S-GEMM)
  unsigned short* Ttb   = bfp;             //  ALIAS Qpb
  unsigned short* Wqt   = bfp + 2097152;   //    262,144
  unsigned short* Cw3b  = bfp + 2359296;   //  8,388,608 (dead after S-GEMM)
  unsigned short* Prow  = bfp + 2359296;   //  ALIAS Cw3b
  unsigned short* Qpbt  = bfp + 10747904;  //  2,097,152
  unsigned short* PcolT = bfp + 12845056;  //  8,388,608
  unsigned short* Cbt   = (unsigned short*)S;  // built after S is dead (16MB)

  // --- operand prep ---
  cast8<<<1024, 256, 0, stream>>>(Q, Qb);                       // Qb[j][b][d]
  transbf<<<dim3(8, 8, 1), 256, 0, stream>>>(Wq, Wqt, DM, DM, 0, 0); // Wqt[n][d]
  build_cw3<<<4096, 256, 0, stream>>>(C, w3, Cw3b);             // Cw3b[b][i][d]
  rowdot<1><<<4096, 256, 0, stream>>>(C, w1, c1);

  // --- Qp = Q @ Wq + bq (MFMA) ---
  mgemm<G_QP, 1, 2><<<dim3(8, 4, BB), 128, 0, stream>>>(
      Qb, BB * DM, DM, Wqt, DM, 0, DM,
      Qp, nullptr, DM, (size_t)QL * DM, bq, nullptr, nullptr);
  cast8<<<1024, 256, 0, stream>>>(Qp, Qpb);                     // Qpb[b][j][d]
  transbf<<<dim3(8, 8, BB), 256, 0, stream>>>(Qp, Qpbt, DM, QL,
                                              (size_t)QL * DM, (size_t)DM * QL);
  rowdot<0><<<1024, 256, 0, stream>>>(Qp, w2, q2);

  // --- S = (C*w3) @ Qp^T + c1 + q2 + b (MFMA) ---
  mgemm<G_S, 2, 2><<<dim3(16, 4, BB), 256, 0, stream>>>(
      Cw3b, DM, (size_t)CL * DM, Qpb, DM, (size_t)QL * DM, DM,
      S, nullptr, QL, (size_t)CL * QL, c1, q2, bs);

  // --- softmax stats (fp32) ---
  row_stats<<<4096, 256, 0, stream>>>(S, Qm, rmax, rinv);
  col_part<<<dim3(16, CH), 256, 0, stream>>>(S, Cm, pmax, psum);
  col_comb<<<16, 256, 0, stream>>>(pmax, psum, cmax, cinv);

  // --- P matrices (bf16) ---
  build_prow<<<4096, 256, 0, stream>>>(S, Qm, rmax, rinv, Prow);  // [b][i][j]
  build_pcolt<<<dim3(32, 8, BB), 256, 0, stream>>>(S, Cm, cmax, cinv, PcolT); // [b][j][i]

  // --- Cbt[b][d][i] = bf16(C[i][b][d])  (into dead S region) ---
  transbf<<<dim3(32, 8, BB), 256, 0, stream>>>(C, Cbt, BB * DM, CL,
                                               DM, (size_t)DM * CL);

  // --- Tt[b][n][j] = sum_i Cbt[b][n][i] * P_col[b][i][j]  (K=2048, bf16 out)
  mgemm<G_TT, 1, 2><<<dim3(8, 4, BB), 128, 0, stream>>>(
      Cbt, CL, (size_t)DM * CL, PcolT, CL, (size_t)QL * CL, CL,
      nullptr, Ttb, QL, (size_t)DM * QL, nullptr, nullptr, nullptr);

  // --- A = P_row @ Qp -> out slot 1 ---
  mgemm<G_SLOT, 2, 2><<<dim3(16, 4, BB), 256, 0, stream>>>(
      Prow, QL, (size_t)CL * QL, Qpbt, QL, (size_t)DM * QL, QL,
      out + 512, nullptr, BB * 4 * DM, (size_t)4 * DM, nullptr, nullptr, nullptr);

  // --- Bm = P_row @ T -> out slot 3 ---
  mgemm<G_SLOT, 2, 2><<<dim3(16, 4, BB), 256, 0, stream>>>(
      Prow, QL, (size_t)CL * QL, Ttb, QL, (size_t)DM * QL, QL,
      out + 1536, nullptr, BB * 4 * DM, (size_t)4 * DM, nullptr, nullptr, nullptr);

  // --- slot0 = C, slot2 = C*A, slot3 = C*Bm ---
  assemble<<<8192, 256, 0, stream>>>(C, out);
}

// Round 6
// 477.996 us; speedup vs baseline: 2.2497x; 1.0544x over previous
//
#include <hip/hip_runtime.h>
#include <math.h>

// Problem constants (fixed-shape)
constexpr int BB = 8;      // batch
constexpr int CL = 2048;   // c_len
constexpr int QL = 512;    // q_len
constexpr int DM = 512;    // dim

typedef short          bf16x8 __attribute__((ext_vector_type(8)));
typedef unsigned short us8    __attribute__((ext_vector_type(8)));
typedef float          f32x4  __attribute__((ext_vector_type(4)));

__device__ __forceinline__ unsigned short f2b(float f) {
  union { float f; unsigned u; } v; v.f = f;
  return (unsigned short)((v.u + 0x7FFFu + ((v.u >> 16) & 1u)) >> 16);
}

// ---------------------------------------------------------------------------
// MFMA bf16 GEMM template. Both operands stored row-major over K:
//   A[b][row][k] (stride sA, batch batA), B[b][col][k] (stride sB, batch batB)
// Wave = 64x64 tile (4x4 frags of 16x16x32), block = WR x WC waves.
// Frag conventions (gfx950 mfma_f32_16x16x32_bf16):
//   A/B: lane l holds 8 bf16 at [row/col = l&15][k = (l>>4)*8 .. +8)
//   D:   col = lane&15, row = (lane>>4)*4 + reg   (HW-verified, m89/m91)
// Modes:
//  G_QP : +bq[col]; writes Qp fp32 AND Qpb bf16
//  G_S  : +c1[row]+q2[col]+b -> fp32
//  G_TT : bf16 out
//  G_A  : v=A; reads c=C[row,b,col] (e1); writes out slot0=c, slot1=v, slot2=c*v
//  G_BM : v=Bm; reads c; writes out slot3=c*v
// ---------------------------------------------------------------------------
enum { G_QP = 0, G_S = 1, G_TT = 2, G_A = 3, G_BM = 4 };

template <int MODE, int WR, int WC>
__global__ __launch_bounds__(WR * WC * 64) void mgemm(
    const unsigned short* __restrict__ A, int sA, size_t batA,
    const unsigned short* __restrict__ B, int sB, size_t batB,
    int K,
    float* __restrict__ Of, unsigned short* __restrict__ Ob,
    int sD, size_t batD,
    const float* __restrict__ e1, const float* __restrict__ e2,
    const float* __restrict__ e3)
{
  const int tid = threadIdx.x, b = blockIdx.z;
  const int wave = tid >> 6, lane = tid & 63;
  const int wr = wave / WC, wc = wave % WC;
  const int m0 = blockIdx.x * (WR * 64) + wr * 64;
  const int n0 = blockIdx.y * (WC * 64) + wc * 64;
  const int l15 = lane & 15, lk8 = (lane >> 4) * 8;

  const unsigned short* ap = A + batA * b + (size_t)(m0 + l15) * sA + lk8;
  const unsigned short* bp = B + batB * b + (size_t)(n0 + l15) * sB + lk8;

  f32x4 acc[4][4];
  #pragma unroll
  for (int mr = 0; mr < 4; mr++)
    #pragma unroll
    for (int nc = 0; nc < 4; nc++) acc[mr][nc] = (f32x4){0.f, 0.f, 0.f, 0.f};

  for (int k0 = 0; k0 < K; k0 += 32) {
    bf16x8 af[4], bf[4];
    #pragma unroll
    for (int mr = 0; mr < 4; mr++)
      af[mr] = *(const bf16x8*)(ap + (size_t)mr * 16 * sA + k0);
    #pragma unroll
    for (int nc = 0; nc < 4; nc++)
      bf[nc] = *(const bf16x8*)(bp + (size_t)nc * 16 * sB + k0);
    #pragma unroll
    for (int mr = 0; mr < 4; mr++)
      #pragma unroll
      for (int nc = 0; nc < 4; nc++)
        acc[mr][nc] = __builtin_amdgcn_mfma_f32_16x16x32_bf16(
            af[mr], bf[nc], acc[mr][nc], 0, 0, 0);
  }

  const int r0 = (lane >> 4) * 4;
  #pragma unroll
  for (int mr = 0; mr < 4; mr++) {
    #pragma unroll
    for (int nc = 0; nc < 4; nc++) {
      const int col = n0 + nc * 16 + l15;
      float addc = 0.f;
      if constexpr (MODE == G_QP) addc = e2[col];
      if constexpr (MODE == G_S)  addc = e2[b * QL + col] + e3[0];
      #pragma unroll
      for (int r = 0; r < 4; r++) {
        const int row = m0 + mr * 16 + r0 + r;
        float v = acc[mr][nc][r] + addc;
        if constexpr (MODE == G_S) {
          v += e1[b * CL + row];
          Of[batD * b + (size_t)row * sD + col] = v;
        } else if constexpr (MODE == G_QP) {
          Of[batD * b + (size_t)row * sD + col] = v;
          Ob[batD * b + (size_t)row * sD + col] = f2b(v);
        } else if constexpr (MODE == G_TT) {
          Ob[batD * b + (size_t)row * sD + col] = f2b(v);
        } else {  // G_A / G_BM: out layout [c_len][B][4*DM]
          const size_t obase = ((size_t)row * BB + b) * (4 * DM) + col;
          const float c = e1[((size_t)row * BB + b) * DM + col];
          if constexpr (MODE == G_A) {
            Of[obase] = c;
            Of[obase + DM] = v;
            Of[obase + 2 * DM] = c * v;
          } else {
            Of[obase + 3 * DM] = c * v;
          }
        }
      }
    }
  }
}

// ---------------------------------------------------------------------------
// Elementwise fp32 -> bf16 cast, 8 elems/thread (layout preserved).
// ---------------------------------------------------------------------------
__global__ __launch_bounds__(256) void cast8(const float* __restrict__ src,
                                             unsigned short* __restrict__ dst)
{
  const int g = blockIdx.x * 256 + threadIdx.x;
  const float4 v0 = *((const float4*)src + g * 2);
  const float4 v1 = *((const float4*)src + g * 2 + 1);
  us8 r = {f2b(v0.x), f2b(v0.y), f2b(v0.z), f2b(v0.w),
           f2b(v1.x), f2b(v1.y), f2b(v1.z), f2b(v1.w)};
  *((us8*)dst + g) = r;
}

// ---------------------------------------------------------------------------
// Fused: Cw3b[b][i][d] = bf16(C[i][b][d]*w3[d]) AND c1[b*CL+i] = w1 . C_i
// One wave per (b,i) row (8 elems/lane), shuffle-tree for the dot.
// ---------------------------------------------------------------------------
__global__ __launch_bounds__(256) void build_cw3c(
    const float* __restrict__ C, const float* __restrict__ w3,
    const float* __restrict__ w1, unsigned short* __restrict__ dst,
    float* __restrict__ c1)
{
  const int g = blockIdx.x * 256 + threadIdx.x;   // 16384 rows * 64
  const int orow = g >> 6, d0 = (g & 63) * 8;     // orow = b*CL + i
  const int b = orow >> 11, i = orow & 2047;
  const float* s = C + ((size_t)i * BB + b) * DM + d0;
  const float4 v0 = *(const float4*)s, v1 = *(const float4*)(s + 4);
  const float4 w30 = *(const float4*)(w3 + d0), w31 = *(const float4*)(w3 + d0 + 4);
  const float4 w10 = *(const float4*)(w1 + d0), w11 = *(const float4*)(w1 + d0 + 4);
  us8 r = {f2b(v0.x * w30.x), f2b(v0.y * w30.y), f2b(v0.z * w30.z), f2b(v0.w * w30.w),
           f2b(v1.x * w31.x), f2b(v1.y * w31.y), f2b(v1.z * w31.z), f2b(v1.w * w31.w)};
  *(us8*)(dst + (size_t)orow * DM + d0) = r;
  float sdot = v0.x * w10.x + v0.y * w10.y + v0.z * w10.z + v0.w * w10.w +
               v1.x * w11.x + v1.y * w11.y + v1.z * w11.z + v1.w * w11.w;
  #pragma unroll
  for (int off = 32; off; off >>= 1) sdot += __shfl_xor(sdot, off);
  if ((g & 63) == 0) c1[orow] = sdot;
}

// ---------------------------------------------------------------------------
// Tiled 64x64 transpose, fp32 src -> bf16 dst: dst[b][c][r] = src[b][r][c].
// ---------------------------------------------------------------------------
__global__ __launch_bounds__(256) void transbf(const float* __restrict__ src,
                                               unsigned short* __restrict__ dst,
                                               int sSrc, int sDst,
                                               size_t batSrc, size_t batDst)
{
  __shared__ float t[64][65];
  const int b = blockIdx.z;
  const int r0 = blockIdx.x * 64, c0 = blockIdx.y * 64;
  const int tx = threadIdx.x & 63, ty = threadIdx.x >> 6;  // ty 0..3
  const float* S = src + batSrc * b;
  unsigned short* D = dst + batDst * b;
  #pragma unroll
  for (int rr = 0; rr < 16; rr++) {
    const int r = ty * 16 + rr;
    t[r][tx] = S[(size_t)(r0 + r) * sSrc + c0 + tx];
  }
  __syncthreads();
  #pragma unroll
  for (int rr = 0; rr < 16; rr++) {
    const int c = ty * 16 + rr;
    D[(size_t)(c0 + c) * sDst + r0 + tx] = f2b(t[tx][c]);
  }
}

// ---------------------------------------------------------------------------
// Fused row softmax: stats + P in one S pass. One wave per (b,i) row.
// P_rowb[b][i][j] = Qm[j,b] ? bf16(exp(S-m)*inv) : 0
// ---------------------------------------------------------------------------
__global__ __launch_bounds__(256) void row_softmax(
    const float* __restrict__ S, const int* __restrict__ qm,
    unsigned short* __restrict__ dst)
{
  const int rid = blockIdx.x * 4 + (threadIdx.x >> 6);  // b*CL + i
  const int lane = threadIdx.x & 63;
  const int b = rid >> 11;
  const float* row = S + (size_t)rid * QL;
  const float4 v0 = *(const float4*)(row + lane * 8);
  const float4 v1 = *(const float4*)(row + lane * 8 + 4);
  const float va[8] = {v0.x, v0.y, v0.z, v0.w, v1.x, v1.y, v1.z, v1.w};
  int mk[8];
  float m = -INFINITY;
  #pragma unroll
  for (int e = 0; e < 8; e++) {
    mk[e] = qm[(lane * 8 + e) * BB + b];
    if (mk[e]) m = fmaxf(m, va[e]);
  }
  #pragma unroll
  for (int off = 32; off; off >>= 1) m = fmaxf(m, __shfl_xor(m, off));
  float s = 0.f;
  #pragma unroll
  for (int e = 0; e < 8; e++) if (mk[e]) s += expf(va[e] - m);
  #pragma unroll
  for (int off = 32; off; off >>= 1) s += __shfl_xor(s, off);
  const float iv = 1.f / s;
  us8 r;
  #pragma unroll
  for (int e = 0; e < 8; e++)
    r[e] = mk[e] ? f2b(expf(va[e] - m) * iv) : (unsigned short)0;
  *(us8*)(dst + (size_t)rid * QL + lane * 8) = r;
}

// ---------------------------------------------------------------------------
// P_colTb[b][j][i] = Cm[i,b] ? bf16(exp(S[b][i][j]-cmax[b,j])*cinv[b,j]) : 0
// ---------------------------------------------------------------------------
__global__ __launch_bounds__(256) void build_pcolt(
    const float* __restrict__ Sm, const int* __restrict__ cm,
    const float* __restrict__ cmax, const float* __restrict__ cinv,
    unsigned short* __restrict__ dst)
{
  __shared__ float t[64][65];
  const int b = blockIdx.z;
  const int i0 = blockIdx.x * 64, j0 = blockIdx.y * 64;
  const int tx = threadIdx.x & 63, ty = threadIdx.x >> 6;
  const float* S = Sm + (size_t)b * CL * QL;
  #pragma unroll
  for (int rr = 0; rr < 16; rr++) {
    const int i = ty * 16 + rr;
    t[i][tx] = S[(size_t)(i0 + i) * QL + j0 + tx];
  }
  __syncthreads();
  const int cmv = cm[(i0 + tx) * BB + b];
  #pragma unroll
  for (int rr = 0; rr < 16; rr++) {
    const int j = j0 + ty * 16 + rr;
    const float mj = cmax[b * QL + j], ivj = cinv[b * QL + j];
    const float v = t[tx][ty * 16 + rr];
    dst[(size_t)b * QL * CL + (size_t)j * CL + i0 + tx] =
        cmv ? f2b(expf(v - mj) * ivj) : (unsigned short)0;
  }
}

// ---------------------------------------------------------------------------
// out[row] = dot(mat_row, w), rows of length 512. One wave per row.
// ---------------------------------------------------------------------------
__global__ __launch_bounds__(256) void rowdot(const float* __restrict__ src,
                                              const float* __restrict__ w,
                                              float* __restrict__ out)
{
  const int rid = blockIdx.x * 4 + (threadIdx.x >> 6);
  const int lane = threadIdx.x & 63;
  const float* row = src + (size_t)rid * DM;
  float4 v0 = *(const float4*)(row + lane * 8);
  float4 v1 = *(const float4*)(row + lane * 8 + 4);
  float4 w0 = *(const float4*)(w + lane * 8);
  float4 w1 = *(const float4*)(w + lane * 8 + 4);
  float s = v0.x * w0.x + v0.y * w0.y + v0.z * w0.z + v0.w * w0.w +
            v1.x * w1.x + v1.y * w1.y + v1.z * w1.z + v1.w * w1.w;
  #pragma unroll
  for (int off = 32; off; off >>= 1) s += __shfl_xor(s, off);
  if (lane == 0) out[rid] = s;
}

// ---------------------------------------------------------------------------
// Col softmax stats, chunked over i.
// ---------------------------------------------------------------------------
constexpr int CH = 16;

__global__ __launch_bounds__(256) void col_part(const float* __restrict__ S,
    const int* __restrict__ cm, float* __restrict__ pmax, float* __restrict__ psum)
{
  const int t = blockIdx.x * 256 + threadIdx.x;  // b*QL + j
  const int ch = blockIdx.y;
  const int b = t >> 9, j = t & 511;
  const float* col = S + (size_t)b * CL * QL + j;
  float m = -INFINITY, s = 0.f;
  const int i0 = ch * (CL / CH);
  for (int i = 0; i < CL / CH; i++) {
    const int ig = i0 + i;
    const float v = col[(size_t)ig * QL];
    if (cm[ig * BB + b]) {
      const float nm = fmaxf(m, v);
      s = s * expf(m - nm) + expf(v - nm);
      m = nm;
    }
  }
  pmax[ch * 4096 + t] = m;
  psum[ch * 4096 + t] = s;
}

__global__ __launch_bounds__(256) void col_comb(const float* __restrict__ pmax,
    const float* __restrict__ psum, float* __restrict__ cmax, float* __restrict__ cinv)
{
  const int t = blockIdx.x * 256 + threadIdx.x;
  float m = -INFINITY;
  #pragma unroll
  for (int ch = 0; ch < CH; ch++) m = fmaxf(m, pmax[ch * 4096 + t]);
  float s = 0.f;
  #pragma unroll
  for (int ch = 0; ch < CH; ch++) {
    const float pm = pmax[ch * 4096 + t];
    if (pm > -INFINITY) s += psum[ch * 4096 + t] * expf(pm - m);
  }
  cmax[t] = m;
  cinv[t] = 1.f / s;
}

// ---------------------------------------------------------------------------
extern "C" void kernel_launch(void* const* d_in, const int* in_sizes, int n_in,
                              void* d_out, int out_size, void* d_ws, size_t ws_size,
                              hipStream_t stream)
{
  const float* C  = (const float*)d_in[0];
  const float* Q  = (const float*)d_in[1];
  const int*   Cm = (const int*)d_in[2];
  const int*   Qm = (const int*)d_in[3];
  const float* Wq = (const float*)d_in[4];
  const float* bq = (const float*)d_in[5];
  const float* w1 = (const float*)d_in[6];
  const float* w2 = (const float*)d_in[7];
  const float* w3 = (const float*)d_in[8];
  const float* bs = (const float*)d_in[9];
  float* out = (float*)d_out;
  float* ws  = (float*)d_ws;

  // fp32 region (float offsets)
  float* S    = ws;                 //  8,388,608 (dead after build_pcolt)
  float* Qp   = ws + 8388608;       //  2,097,152
  float* c1   = ws + 10485760;      //  16,384
  float* q2   = ws + 10502144;      //  4,096
  float* cmax = ws + 10506240;      //  4,096
  float* cinv = ws + 10510336;      //  4,096
  float* pmax = ws + 10514432;      //  65,536
  float* psum = ws + 10579968;      //  65,536
  // bf16 region (ushort offsets from bfp); peak d_ws use ~90 MB
  unsigned short* bfp   = (unsigned short*)(ws + 10645504);
  unsigned short* Qb    = bfp;             //  2,097,152 (dead after QP-GEMM)
  unsigned short* Ttb   = bfp;             //  ALIAS Qb
  unsigned short* Wqt   = bfp + 2097152;   //    262,144
  unsigned short* Cw3b  = bfp + 2359296;   //  8,388,608 (dead after S-GEMM)
  unsigned short* Prow  = bfp + 2359296;   //  ALIAS Cw3b
  unsigned short* Qpb   = bfp + 10747904;  //  2,097,152
  unsigned short* Qpbt  = bfp + 12845056;  //  2,097,152
  unsigned short* PcolT = bfp + 14942208;  //  8,388,608
  unsigned short* Cbt   = (unsigned short*)S;  // built after S is dead (16MB)

  // --- operand prep ---
  cast8<<<1024, 256, 0, stream>>>(Q, Qb);                       // Qb[j][b][d]
  transbf<<<dim3(8, 8, 1), 256, 0, stream>>>(Wq, Wqt, DM, DM, 0, 0); // Wqt[n][d]
  build_cw3c<<<4096, 256, 0, stream>>>(C, w3, w1, Cw3b, c1);    // Cw3b + c1

  // --- Qp = Q @ Wq + bq (MFMA; writes fp32 Qp and bf16 Qpb) ---
  mgemm<G_QP, 1, 2><<<dim3(8, 4, BB), 128, 0, stream>>>(
      Qb, BB * DM, DM, Wqt, DM, 0, DM,
      Qp, Qpb, DM, (size_t)QL * DM, nullptr, bq, nullptr);
  transbf<<<dim3(8, 8, BB), 256, 0, stream>>>(Qp, Qpbt, DM, QL,
                                              (size_t)QL * DM, (size_t)DM * QL);
  rowdot<<<1024, 256, 0, stream>>>(Qp, w2, q2);

  // --- S = (C*w3) @ Qp^T + c1 + q2 + b (MFMA) ---
  mgemm<G_S, 2, 2><<<dim3(16, 4, BB), 256, 0, stream>>>(
      Cw3b, DM, (size_t)CL * DM, Qpb, DM, (size_t)QL * DM, DM,
      S, nullptr, QL, (size_t)CL * QL, c1, q2, bs);

  // --- row softmax (fused stats+P) ---
  row_softmax<<<4096, 256, 0, stream>>>(S, Qm, Prow);           // [b][i][j]

  // --- col softmax stats + P^T ---
  col_part<<<dim3(16, CH), 256, 0, stream>>>(S, Cm, pmax, psum);
  col_comb<<<16, 256, 0, stream>>>(pmax, psum, cmax, cinv);
  build_pcolt<<<dim3(32, 8, BB), 256, 0, stream>>>(S, Cm, cmax, cinv, PcolT); // [b][j][i]

  // --- Cbt[b][d][i] = bf16(C[i][b][d])  (into dead S region) ---
  transbf<<<dim3(32, 8, BB), 256, 0, stream>>>(C, Cbt, BB * DM, CL,
                                               DM, (size_t)DM * CL);

  // --- Tt[b][n][j] = sum_i Cbt[b][n][i] * P_col[b][i][j]  (K=2048, bf16 out)
  mgemm<G_TT, 1, 2><<<dim3(8, 4, BB), 128, 0, stream>>>(
      Cbt, CL, (size_t)DM * CL, PcolT, CL, (size_t)QL * CL, CL,
      nullptr, Ttb, QL, (size_t)DM * QL, nullptr, nullptr, nullptr);

  // --- A = P_row @ Qp -> out slots 0,1,2 (C, A, C*A) ---
  mgemm<G_A, 2, 2><<<dim3(16, 4, BB), 256, 0, stream>>>(
      Prow, QL, (size_t)CL * QL, Qpbt, QL, (size_t)DM * QL, QL,
      out, nullptr, 0, 0, C, nullptr, nullptr);

  // --- Bm = P_row @ T -> out slot 3 (C*Bm) ---
  mgemm<G_BM, 2, 2><<<dim3(16, 4, BB), 256, 0, stream>>>(
      Prow, QL, (size_t)CL * QL, Ttb, QL, (size_t)DM * QL, QL,
      out, nullptr, 0, 0, C, nullptr, nullptr);
}

// Round 9
// 414.801 us; speedup vs baseline: 2.5925x; 1.1523x over previous
//
#include <hip/hip_runtime.h>
#include <math.h>

// Problem constants (fixed-shape)
constexpr int BB = 8;      // batch
constexpr int CL = 2048;   // c_len
constexpr int QL = 512;    // q_len
constexpr int DM = 512;    // dim

typedef short          bf16x8 __attribute__((ext_vector_type(8)));
typedef unsigned short us8    __attribute__((ext_vector_type(8)));
typedef float          f32x4  __attribute__((ext_vector_type(4)));

__device__ __forceinline__ unsigned short f2b(float f) {
  union { float f; unsigned u; } v; v.f = f;
  return (unsigned short)((v.u + 0x7FFFu + ((v.u >> 16) & 1u)) >> 16);
}

// ---------------------------------------------------------------------------
// MFMA bf16 GEMM template (A[b][row][k], B[b][col][k], K-major both).
// Wave = 64x64 tile (4x4 frags of 16x16x32), block = WR x WC waves.
// D layout: col = lane&15, row = (lane>>4)*4 + reg (HW-verified m89/m91).
// Modes:
//  G_QP : +bq[col]; writes Qp fp32 AND Qpb bf16
//  G_TT : bf16 out
//  G_A  : v=A; c=C[row,b,col] (e1); out slot0=c, slot1=v, slot2=c*v
//  G_BM : v=Bm; out slot3=c*v
// ---------------------------------------------------------------------------
enum { G_QP = 0, G_TT = 1, G_A = 2, G_BM = 3 };

template <int MODE, int WR, int WC>
__global__ __launch_bounds__(WR * WC * 64) void mgemm(
    const unsigned short* __restrict__ A, int sA, size_t batA,
    const unsigned short* __restrict__ B, int sB, size_t batB,
    int K,
    float* __restrict__ Of, unsigned short* __restrict__ Ob,
    int sD, size_t batD,
    const float* __restrict__ e1, const float* __restrict__ e2)
{
  const int tid = threadIdx.x, b = blockIdx.z;
  const int wave = tid >> 6, lane = tid & 63;
  const int wr = wave / WC, wc = wave % WC;
  const int m0 = blockIdx.x * (WR * 64) + wr * 64;
  const int n0 = blockIdx.y * (WC * 64) + wc * 64;
  const int l15 = lane & 15, lk8 = (lane >> 4) * 8;

  const unsigned short* ap = A + batA * b + (size_t)(m0 + l15) * sA + lk8;
  const unsigned short* bp = B + batB * b + (size_t)(n0 + l15) * sB + lk8;

  f32x4 acc[4][4];
  #pragma unroll
  for (int mr = 0; mr < 4; mr++)
    #pragma unroll
    for (int nc = 0; nc < 4; nc++) acc[mr][nc] = (f32x4){0.f, 0.f, 0.f, 0.f};

  for (int k0 = 0; k0 < K; k0 += 32) {
    bf16x8 af[4], bf[4];
    #pragma unroll
    for (int mr = 0; mr < 4; mr++)
      af[mr] = *(const bf16x8*)(ap + (size_t)mr * 16 * sA + k0);
    #pragma unroll
    for (int nc = 0; nc < 4; nc++)
      bf[nc] = *(const bf16x8*)(bp + (size_t)nc * 16 * sB + k0);
    #pragma unroll
    for (int mr = 0; mr < 4; mr++)
      #pragma unroll
      for (int nc = 0; nc < 4; nc++)
        acc[mr][nc] = __builtin_amdgcn_mfma_f32_16x16x32_bf16(
            af[mr], bf[nc], acc[mr][nc], 0, 0, 0);
  }

  const int r0 = (lane >> 4) * 4;
  #pragma unroll
  for (int mr = 0; mr < 4; mr++) {
    #pragma unroll
    for (int nc = 0; nc < 4; nc++) {
      const int col = n0 + nc * 16 + l15;
      float addc = 0.f;
      if constexpr (MODE == G_QP) addc = e2[col];
      #pragma unroll
      for (int r = 0; r < 4; r++) {
        const int row = m0 + mr * 16 + r0 + r;
        float v = acc[mr][nc][r] + addc;
        if constexpr (MODE == G_QP) {
          Of[batD * b + (size_t)row * sD + col] = v;
          Ob[batD * b + (size_t)row * sD + col] = f2b(v);
        } else if constexpr (MODE == G_TT) {
          Ob[batD * b + (size_t)row * sD + col] = f2b(v);
        } else {  // G_A / G_BM: out layout [c_len][B][4*DM]
          const size_t obase = ((size_t)row * BB + b) * (4 * DM) + col;
          const float c = e1[((size_t)row * BB + b) * DM + col];
          if constexpr (MODE == G_A) {
            Of[obase] = c;
            Of[obase + DM] = v;
            Of[obase + 2 * DM] = c * v;
          } else {
            Of[obase + 3 * DM] = c * v;
          }
        }
      }
    }
  }
}

// ---------------------------------------------------------------------------
// s_mega: S-GEMM + full row-softmax (P_row bf16) + column partial stats.
// Block = 8 waves (512 thr); block owns rows [m0,m0+64) x ALL 512 cols.
// Wave w computes cols [w*64, w*64+64). Also writes S fp32 (for pcolt).
// NOTE: Prow aliases Cw3b (A operand) — safe: block (x,b) writes exactly the
// row-range only it reads, and all A reads complete before the epilogue.
// ---------------------------------------------------------------------------
__global__ __launch_bounds__(512) void s_mega(
    const unsigned short* __restrict__ Aop,   // Cw3b [b][i][d]
    const unsigned short* __restrict__ Bop,   // Qpb  [b][j][d]
    const float* __restrict__ c1, const float* __restrict__ q2,
    const float* __restrict__ bsc,
    const int* __restrict__ qm, const int* __restrict__ cm,
    float* __restrict__ S, unsigned short* __restrict__ Prow,
    float* __restrict__ pmax, float* __restrict__ psum)
{
  __shared__ float red[64][9];
  __shared__ float redF[64];
  const int b = blockIdx.z;
  const int m0 = blockIdx.x * 64;
  const int wave = threadIdx.x >> 6, lane = threadIdx.x & 63;
  const int n0 = wave * 64;
  const int l15 = lane & 15, g4 = lane >> 4, lk8 = g4 * 8;

  const unsigned short* ap = Aop + (size_t)b * CL * DM + (size_t)(m0 + l15) * DM + lk8;
  const unsigned short* bp = Bop + (size_t)b * QL * DM + (size_t)(n0 + l15) * DM + lk8;

  f32x4 acc[4][4];
  #pragma unroll
  for (int mr = 0; mr < 4; mr++)
    #pragma unroll
    for (int nc = 0; nc < 4; nc++) acc[mr][nc] = (f32x4){0.f, 0.f, 0.f, 0.f};

  for (int k0 = 0; k0 < DM; k0 += 32) {
    bf16x8 af[4], bf[4];
    #pragma unroll
    for (int mr = 0; mr < 4; mr++)
      af[mr] = *(const bf16x8*)(ap + (size_t)mr * 16 * DM + k0);
    #pragma unroll
    for (int nc = 0; nc < 4; nc++)
      bf[nc] = *(const bf16x8*)(bp + (size_t)nc * 16 * DM + k0);
    #pragma unroll
    for (int mr = 0; mr < 4; mr++)
      #pragma unroll
      for (int nc = 0; nc < 4; nc++)
        acc[mr][nc] = __builtin_amdgcn_mfma_f32_16x16x32_bf16(
            af[mr], bf[nc], acc[mr][nc], 0, 0, 0);
  }

  // epilogue adds + S write (acc becomes final S values, fp32)
  const float sb = bsc[0];
  float q2c[4];
  int qmk[4];
  #pragma unroll
  for (int nc = 0; nc < 4; nc++) {
    const int col = n0 + nc * 16 + l15;
    q2c[nc] = q2[b * QL + col] + sb;
    qmk[nc] = qm[col * BB + b];
  }
  float c1r[4][4];
  int cmk[4][4];
  #pragma unroll
  for (int mr = 0; mr < 4; mr++)
    #pragma unroll
    for (int r = 0; r < 4; r++) {
      const int row = m0 + mr * 16 + g4 * 4 + r;
      c1r[mr][r] = c1[b * CL + row];
      cmk[mr][r] = cm[row * BB + b];
    }
  #pragma unroll
  for (int mr = 0; mr < 4; mr++)
    #pragma unroll
    for (int nc = 0; nc < 4; nc++) {
      const int col = n0 + nc * 16 + l15;
      #pragma unroll
      for (int r = 0; r < 4; r++) {
        const int row = m0 + mr * 16 + g4 * 4 + r;
        const float v = acc[mr][nc][r] + q2c[nc] + c1r[mr][r];
        acc[mr][nc][r] = v;
        S[(size_t)(b * CL + row) * QL + col] = v;
      }
    }

  // ---- row max (masked by Qm over cols) ----
  #pragma unroll
  for (int mr = 0; mr < 4; mr++)
    #pragma unroll
    for (int r = 0; r < 4; r++) {
      float m = -INFINITY;
      #pragma unroll
      for (int nc = 0; nc < 4; nc++)
        if (qmk[nc]) m = fmaxf(m, acc[mr][nc][r]);
      #pragma unroll
      for (int off = 1; off < 16; off <<= 1) m = fmaxf(m, __shfl_xor(m, off));
      if (l15 == 0) red[mr * 16 + g4 * 4 + r][wave] = m;
    }
  __syncthreads();
  if (threadIdx.x < 64) {  // wave 0: finalize per-row max
    float m = -INFINITY;
    #pragma unroll
    for (int w = 0; w < 8; w++) m = fmaxf(m, red[threadIdx.x][w]);
    redF[threadIdx.x] = m;
  }
  __syncthreads();
  // ---- row sum of exp ----
  float ev[4][4][4];
  #pragma unroll
  for (int mr = 0; mr < 4; mr++)
    #pragma unroll
    for (int r = 0; r < 4; r++) {
      const float M = redF[mr * 16 + g4 * 4 + r];
      float s = 0.f;
      #pragma unroll
      for (int nc = 0; nc < 4; nc++) {
        const float e = qmk[nc] ? __expf(acc[mr][nc][r] - M) : 0.f;
        ev[mr][nc][r] = e;
        s += e;
      }
      #pragma unroll
      for (int off = 1; off < 16; off <<= 1) s += __shfl_xor(s, off);
      if (l15 == 0) red[mr * 16 + g4 * 4 + r][wave] = s;
    }
  __syncthreads();
  if (threadIdx.x < 64) {
    float s = 0.f;
    #pragma unroll
    for (int w = 0; w < 8; w++) s += red[threadIdx.x][w];
    redF[threadIdx.x] = 1.f / s;
  }
  __syncthreads();
  // ---- write P_row bf16 ----
  #pragma unroll
  for (int mr = 0; mr < 4; mr++)
    #pragma unroll
    for (int r = 0; r < 4; r++) {
      const int row = m0 + mr * 16 + g4 * 4 + r;
      const float iv = redF[mr * 16 + g4 * 4 + r];
      #pragma unroll
      for (int nc = 0; nc < 4; nc++) {
        const int col = n0 + nc * 16 + l15;
        Prow[(size_t)(b * CL + row) * QL + col] =
            qmk[nc] ? f2b(ev[mr][nc][r] * iv) : (unsigned short)0;
      }
    }

  // ---- column partial (max, sum) over this block's 64 rows (mask Cm) ----
  #pragma unroll
  for (int nc = 0; nc < 4; nc++) {
    float m = -INFINITY, s = 0.f;
    #pragma unroll
    for (int mr = 0; mr < 4; mr++)
      #pragma unroll
      for (int r = 0; r < 4; r++)
        if (cmk[mr][r]) {
          const float x = acc[mr][nc][r];
          const float nm = fmaxf(m, x);
          s = s * __expf(m - nm) + __expf(x - nm);
          m = nm;
        }
    #pragma unroll
    for (int off = 16; off < 64; off <<= 1) {
      const float om = __shfl_xor(m, off);
      const float os = __shfl_xor(s, off);
      const float nm = fmaxf(m, om);
      if (nm > -INFINITY)
        s = s * __expf(m - nm) + os * __expf(om - nm);
      else
        s = 0.f;
      m = nm;
    }
    if (g4 == 0) {
      const int idx = blockIdx.x * (BB * QL) + b * QL + n0 + nc * 16 + l15;
      pmax[idx] = m;
      psum[idx] = s;
    }
  }
}

// ---------------------------------------------------------------------------
// Elementwise fp32 -> bf16 cast, 8 elems/thread (layout preserved).
// ---------------------------------------------------------------------------
__global__ __launch_bounds__(256) void cast8(const float* __restrict__ src,
                                             unsigned short* __restrict__ dst)
{
  const int g = blockIdx.x * 256 + threadIdx.x;
  const float4 v0 = *((const float4*)src + g * 2);
  const float4 v1 = *((const float4*)src + g * 2 + 1);
  us8 r = {f2b(v0.x), f2b(v0.y), f2b(v0.z), f2b(v0.w),
           f2b(v1.x), f2b(v1.y), f2b(v1.z), f2b(v1.w)};
  *((us8*)dst + g) = r;
}

// ---------------------------------------------------------------------------
// Fused: Cw3b[b][i][d] = bf16(C[i][b][d]*w3[d]) AND c1[b*CL+i] = w1 . C_i
// ---------------------------------------------------------------------------
__global__ __launch_bounds__(256) void build_cw3c(
    const float* __restrict__ C, const float* __restrict__ w3,
    const float* __restrict__ w1, unsigned short* __restrict__ dst,
    float* __restrict__ c1)
{
  const int g = blockIdx.x * 256 + threadIdx.x;   // 16384 rows * 64
  const int orow = g >> 6, d0 = (g & 63) * 8;     // orow = b*CL + i
  const int b = orow >> 11, i = orow & 2047;
  const float* s = C + ((size_t)i * BB + b) * DM + d0;
  const float4 v0 = *(const float4*)s, v1 = *(const float4*)(s + 4);
  const float4 w30 = *(const float4*)(w3 + d0), w31 = *(const float4*)(w3 + d0 + 4);
  const float4 w10 = *(const float4*)(w1 + d0), w11 = *(const float4*)(w1 + d0 + 4);
  us8 r = {f2b(v0.x * w30.x), f2b(v0.y * w30.y), f2b(v0.z * w30.z), f2b(v0.w * w30.w),
           f2b(v1.x * w31.x), f2b(v1.y * w31.y), f2b(v1.z * w31.z), f2b(v1.w * w31.w)};
  *(us8*)(dst + (size_t)orow * DM + d0) = r;
  float sdot = v0.x * w10.x + v0.y * w10.y + v0.z * w10.z + v0.w * w10.w +
               v1.x * w11.x + v1.y * w11.y + v1.z * w11.z + v1.w * w11.w;
  #pragma unroll
  for (int off = 32; off; off >>= 1) sdot += __shfl_xor(sdot, off);
  if ((g & 63) == 0) c1[orow] = sdot;
}

// ---------------------------------------------------------------------------
// Tiled 64x64 transpose, fp32 src -> bf16 dst: dst[b][c][r] = src[b][r][c].
// ---------------------------------------------------------------------------
__global__ __launch_bounds__(256) void transbf(const float* __restrict__ src,
                                               unsigned short* __restrict__ dst,
                                               int sSrc, int sDst,
                                               size_t batSrc, size_t batDst)
{
  __shared__ float t[64][65];
  const int b = blockIdx.z;
  const int r0 = blockIdx.x * 64, c0 = blockIdx.y * 64;
  const int tx = threadIdx.x & 63, ty = threadIdx.x >> 6;  // ty 0..3
  const float* S = src + batSrc * b;
  unsigned short* D = dst + batDst * b;
  #pragma unroll
  for (int rr = 0; rr < 16; rr++) {
    const int r = ty * 16 + rr;
    t[r][tx] = S[(size_t)(r0 + r) * sSrc + c0 + tx];
  }
  __syncthreads();
  #pragma unroll
  for (int rr = 0; rr < 16; rr++) {
    const int c = ty * 16 + rr;
    D[(size_t)(c0 + c) * sDst + r0 + tx] = f2b(t[tx][c]);
  }
}

// ---------------------------------------------------------------------------
// P_colTb[b][j][i] = Cm[i,b] ? bf16(exp(S[b][i][j]-cmax[b,j])*cinv[b,j]) : 0
// ---------------------------------------------------------------------------
__global__ __launch_bounds__(256) void build_pcolt(
    const float* __restrict__ Sm, const int* __restrict__ cm,
    const float* __restrict__ cmax, const float* __restrict__ cinv,
    unsigned short* __restrict__ dst)
{
  __shared__ float t[64][65];
  const int b = blockIdx.z;
  const int i0 = blockIdx.x * 64, j0 = blockIdx.y * 64;
  const int tx = threadIdx.x & 63, ty = threadIdx.x >> 6;
  const float* S = Sm + (size_t)b * CL * QL;
  #pragma unroll
  for (int rr = 0; rr < 16; rr++) {
    const int i = ty * 16 + rr;
    t[i][tx] = S[(size_t)(i0 + i) * QL + j0 + tx];
  }
  __syncthreads();
  const int cmv = cm[(i0 + tx) * BB + b];
  #pragma unroll
  for (int rr = 0; rr < 16; rr++) {
    const int j = j0 + ty * 16 + rr;
    const float mj = cmax[b * QL + j], ivj = cinv[b * QL + j];
    const float v = t[tx][ty * 16 + rr];
    dst[(size_t)b * QL * CL + (size_t)j * CL + i0 + tx] =
        cmv ? f2b(__expf(v - mj) * ivj) : (unsigned short)0;
  }
}

// ---------------------------------------------------------------------------
// out[row] = dot(mat_row, w), rows of length 512. One wave per row.
// ---------------------------------------------------------------------------
__global__ __launch_bounds__(256) void rowdot(const float* __restrict__ src,
                                              const float* __restrict__ w,
                                              float* __restrict__ out)
{
  const int rid = blockIdx.x * 4 + (threadIdx.x >> 6);
  const int lane = threadIdx.x & 63;
  const float* row = src + (size_t)rid * DM;
  float4 v0 = *(const float4*)(row + lane * 8);
  float4 v1 = *(const float4*)(row + lane * 8 + 4);
  float4 w0 = *(const float4*)(w + lane * 8);
  float4 w1 = *(const float4*)(w + lane * 8 + 4);
  float s = v0.x * w0.x + v0.y * w0.y + v0.z * w0.z + v0.w * w0.w +
            v1.x * w1.x + v1.y * w1.y + v1.z * w1.z + v1.w * w1.w;
  #pragma unroll
  for (int off = 32; off; off >>= 1) s += __shfl_xor(s, off);
  if (lane == 0) out[rid] = s;
}

// ---------------------------------------------------------------------------
// Combine 32 column-chunk partials -> cmax/cinv.
// ---------------------------------------------------------------------------
constexpr int CH = 32;

__global__ __launch_bounds__(256) void col_comb(const float* __restrict__ pmax,
    const float* __restrict__ psum, float* __restrict__ cmax, float* __restrict__ cinv)
{
  const int t = blockIdx.x * 256 + threadIdx.x;
  float m = -INFINITY;
  #pragma unroll
  for (int ch = 0; ch < CH; ch++) m = fmaxf(m, pmax[ch * 4096 + t]);
  float s = 0.f;
  #pragma unroll
  for (int ch = 0; ch < CH; ch++) {
    const float pm = pmax[ch * 4096 + t];
    if (pm > -INFINITY) s += psum[ch * 4096 + t] * __expf(pm - m);
  }
  cmax[t] = m;
  cinv[t] = 1.f / s;
}

// ---------------------------------------------------------------------------
extern "C" void kernel_launch(void* const* d_in, const int* in_sizes, int n_in,
                              void* d_out, int out_size, void* d_ws, size_t ws_size,
                              hipStream_t stream)
{
  const float* C  = (const float*)d_in[0];
  const float* Q  = (const float*)d_in[1];
  const int*   Cm = (const int*)d_in[2];
  const int*   Qm = (const int*)d_in[3];
  const float* Wq = (const float*)d_in[4];
  const float* bq = (const float*)d_in[5];
  const float* w1 = (const float*)d_in[6];
  const float* w2 = (const float*)d_in[7];
  const float* w3 = (const float*)d_in[8];
  const float* bs = (const float*)d_in[9];
  float* out = (float*)d_out;
  float* ws  = (float*)d_ws;

  // fp32 region (float offsets)
  float* S    = ws;                 //  8,388,608 (dead after build_pcolt)
  float* Qp   = ws + 8388608;       //  2,097,152
  float* c1   = ws + 10485760;      //  16,384
  float* q2   = ws + 10502144;      //  4,096
  float* cmax = ws + 10506240;      //  4,096
  float* cinv = ws + 10510336;      //  4,096
  float* pmax = ws + 10514432;      // 131,072 (32 chunks x 4096)
  float* psum = ws + 10645504;      // 131,072
  // bf16 region (ushort offsets from bfp); peak d_ws use ~86 MB
  unsigned short* bfp   = (unsigned short*)(ws + 10776576);
  unsigned short* Qb    = bfp;             //  2,097,152 (dead after QP-GEMM)
  unsigned short* Ttb   = bfp;             //  ALIAS Qb
  unsigned short* Wqt   = bfp + 2097152;   //    262,144
  unsigned short* Cw3b  = bfp + 2359296;   //  8,388,608 (dead after s_mega reads)
  unsigned short* Prow  = bfp + 2359296;   //  ALIAS Cw3b (written by s_mega)
  unsigned short* Qpb   = bfp + 10747904;  //  2,097,152
  unsigned short* Qpbt  = bfp + 12845056;  //  2,097,152
  unsigned short* PcolT = bfp + 14942208;  //  8,388,608
  unsigned short* Cbt   = (unsigned short*)S;  // built after S is dead (16MB)

  // --- operand prep ---
  cast8<<<1024, 256, 0, stream>>>(Q, Qb);                       // Qb[j][b][d]
  transbf<<<dim3(8, 8, 1), 256, 0, stream>>>(Wq, Wqt, DM, DM, 0, 0); // Wqt[n][d]
  build_cw3c<<<4096, 256, 0, stream>>>(C, w3, w1, Cw3b, c1);    // Cw3b + c1

  // --- Qp = Q @ Wq + bq (MFMA; writes fp32 Qp and bf16 Qpb) ---
  mgemm<G_QP, 1, 2><<<dim3(8, 4, BB), 128, 0, stream>>>(
      Qb, BB * DM, DM, Wqt, DM, 0, DM,
      Qp, Qpb, DM, (size_t)QL * DM, nullptr, bq);
  transbf<<<dim3(8, 8, BB), 256, 0, stream>>>(Qp, Qpbt, DM, QL,
                                              (size_t)QL * DM, (size_t)DM * QL);
  rowdot<<<1024, 256, 0, stream>>>(Qp, w2, q2);

  // --- s_mega: S fp32 + row softmax (Prow) + col partials ---
  s_mega<<<dim3(32, 1, BB), 512, 0, stream>>>(
      Cw3b, Qpb, c1, q2, bs, Qm, Cm, S, Prow, pmax, psum);

  // --- finalize col softmax, build P_col^T ---
  col_comb<<<16, 256, 0, stream>>>(pmax, psum, cmax, cinv);
  build_pcolt<<<dim3(32, 8, BB), 256, 0, stream>>>(S, Cm, cmax, cinv, PcolT); // [b][j][i]

  // --- Cbt[b][d][i] = bf16(C[i][b][d])  (into dead S region) ---
  transbf<<<dim3(32, 8, BB), 256, 0, stream>>>(C, Cbt, BB * DM, CL,
                                               DM, (size_t)DM * CL);

  // --- Tt[b][n][j] = sum_i Cbt[b][n][i] * P_col[b][i][j]  (K=2048, bf16 out)
  mgemm<G_TT, 1, 2><<<dim3(8, 4, BB), 128, 0, stream>>>(
      Cbt, CL, (size_t)DM * CL, PcolT, CL, (size_t)QL * CL, CL,
      nullptr, Ttb, QL, (size_t)DM * QL, nullptr, nullptr);

  // --- A = P_row @ Qp -> out slots 0,1,2 (C, A, C*A) ---
  mgemm<G_A, 2, 2><<<dim3(16, 4, BB), 256, 0, stream>>>(
      Prow, QL, (size_t)CL * QL, Qpbt, QL, (size_t)DM * QL, QL,
      out, nullptr, 0, 0, C, nullptr);

  // --- Bm = P_row @ T -> out slot 3 (C*Bm) ---
  mgemm<G_BM, 2, 2><<<dim3(16, 4, BB), 256, 0, stream>>>(
      Prow, QL, (size_t)CL * QL, Ttb, QL, (size_t)DM * QL, QL,
      out, nullptr, 0, 0, C, nullptr);
}